// Round 4
// baseline (264.618 us; speedup 1.0000x reference)
//
#include <hip/hip_runtime.h>

#define TT 2048
#define BLOCK 256
#define WAVES (BLOCK / 64)   // 4 rows per block, one per wave

typedef float floatx4 __attribute__((ext_vector_type(4)));  // native vec type for nt builtins

__device__ __forceinline__ float fast_sigmoid(float x) {
    // 1/(1+exp(-x)); v_rcp_f32 rel-err ~1e-7, fine vs 2.8e-3 threshold
    return __builtin_amdgcn_rcpf(1.0f + __expf(-x));
}

__device__ __forceinline__ void nt_store4(float* p, float x, float y, float z, float w) {
    // non-temporal 16B store: global_store_dwordx4 ... nt (bypass L2 churn;
    // 268 MB output is 8x aggregate L2, no reuse ever)
    floatx4 v = {x, y, z, w};
    __builtin_nontemporal_store(v, (floatx4*)p);
}

__global__ __launch_bounds__(BLOCK) void score_branch_kernel(
    const float* __restrict__ logits, const int* __restrict__ seq_len,
    float* __restrict__ out)
{
    __shared__ float s_scores[TT];

    const int b    = blockIdx.y;
    const int row0 = blockIdx.x * WAVES;
    const int tid  = threadIdx.x;
    const int lane = tid & 63;
    const int wv   = tid >> 6;
    const int L    = seq_len[b];   // in [1, TT]

    // Stage scores = sigmoid(logits[b,:]) into LDS, float4-vectorized.
    const float4* lg4 = (const float4*)(logits + (size_t)b * TT);
    float4* s4 = (float4*)s_scores;
    #pragma unroll
    for (int k = 0; k < TT / (BLOCK * 4); ++k) {   // 2 iters
        int idx4 = tid + k * BLOCK;
        float4 v = lg4[idx4];
        float4 s;
        s.x = fast_sigmoid(v.x);
        s.y = fast_sigmoid(v.y);
        s.z = fast_sigmoid(v.z);
        s.w = fast_sigmoid(v.w);
        s4[idx4] = s;
    }
    __syncthreads();   // the ONLY block barrier — waves free-run after this

    const int i = row0 + wv;   // this wave's row
    float* orow = out + ((size_t)b * TT + (size_t)i) * TT;

    if (i >= L) {
        // invalid row -> exact zeros (d_out is poisoned); wave-uniform branch
        #pragma unroll
        for (int q = 0; q < 8; ++q)
            nt_store4(orow + (q * 64 + lane) * 4, 0.f, 0.f, 0.f, 0.f);
        return;
    }

    const float si = s_scores[i];

    // Each lane: 8 float4 groups, j4 = q*64 + lane (coalesced), 32 elems total.
    float4 e4[8];
    float partial = 0.f;
    #pragma unroll
    for (int q = 0; q < 8; ++q) {
        const int idx4 = q * 64 + lane;
        float4 sj = s4[idx4];
        const int j0 = idx4 * 4;
        float vals[4] = {sj.x, sj.y, sj.z, sj.w};
        float* ev = (float*)&e4[q];
        #pragma unroll
        for (int qq = 0; qq < 4; ++qq) {
            float d  = si - vals[qq];
            float t  = fmaf(fabsf(d), -10.0f, 5.0f);   // (0.5-|d|)/0.1
            float p  = fast_sigmoid(t);                // rel in (0,1)
            float ee = __expf(p);                      // rel<1 -> no max-sub needed
            ee = (j0 + qq < L) ? ee : 0.0f;            // masked cols -> exact 0
            ev[qq] = ee;
            partial += ee;
        }
    }

    // wave-private butterfly reduction — no LDS, no barrier
    #pragma unroll
    for (int off = 32; off > 0; off >>= 1)
        partial += __shfl_xor(partial, off, 64);
    const float inv = __builtin_amdgcn_rcpf(partial);

    #pragma unroll
    for (int q = 0; q < 8; ++q) {
        nt_store4(orow + (q * 64 + lane) * 4,
                  e4[q].x * inv, e4[q].y * inv, e4[q].z * inv, e4[q].w * inv);
    }
}

extern "C" void kernel_launch(void* const* d_in, const int* in_sizes, int n_in,
                              void* d_out, int out_size, void* d_ws, size_t ws_size,
                              hipStream_t stream) {
    const float* logits  = (const float*)d_in[0];   // [B, T, 1] fp32
    const int*   seq_len = (const int*)d_in[1];     // [B] int32
    float*       out     = (float*)d_out;           // [B, T, T] fp32

    const int B = in_sizes[1];                      // 16
    dim3 grid(TT / WAVES, B);                       // (512, 16) = 8192 blocks
    score_branch_kernel<<<grid, dim3(BLOCK), 0, stream>>>(logits, seq_len, out);
}

// Round 5
// 257.403 us; speedup vs baseline: 1.0280x; 1.0280x over previous
//
#include <hip/hip_runtime.h>

#define TT 2048
#define BLOCK 256
#define WAVES (BLOCK / 64)   // 4 rows per block, one per wave

__device__ __forceinline__ float fast_sigmoid(float x) {
    // 1/(1+exp(-x)); v_rcp_f32 rel-err ~1e-7, fine vs 2.8e-3 threshold
    return __builtin_amdgcn_rcpf(1.0f + __expf(-x));
}

__global__ __launch_bounds__(BLOCK) void score_branch_kernel(
    const float* __restrict__ logits, const int* __restrict__ seq_len,
    float* __restrict__ out)
{
    __shared__ float s_scores[TT];

    const int b    = blockIdx.y;
    const int row0 = blockIdx.x * WAVES;
    const int tid  = threadIdx.x;
    const int lane = tid & 63;
    const int wv   = tid >> 6;
    const int L    = seq_len[b];   // in [1, TT]

    // Stage scores = sigmoid(logits[b,:]) into LDS, float4-vectorized.
    const float4* lg4 = (const float4*)(logits + (size_t)b * TT);
    float4* s4 = (float4*)s_scores;
    #pragma unroll
    for (int k = 0; k < TT / (BLOCK * 4); ++k) {   // 2 iters
        int idx4 = tid + k * BLOCK;
        float4 v = lg4[idx4];
        float4 s;
        s.x = fast_sigmoid(v.x);
        s.y = fast_sigmoid(v.y);
        s.z = fast_sigmoid(v.z);
        s.w = fast_sigmoid(v.w);
        s4[idx4] = s;
    }
    __syncthreads();   // the ONLY block barrier — waves free-run after this

    const int i = row0 + wv;   // this wave's row
    float4* orow4 = (float4*)(out + ((size_t)b * TT + (size_t)i) * TT);

    if (i >= L) {
        // invalid row -> exact zeros (d_out is poisoned); wave-uniform branch
        float4 z = make_float4(0.f, 0.f, 0.f, 0.f);
        #pragma unroll
        for (int q = 0; q < 8; ++q)
            orow4[q * 64 + lane] = z;
        return;
    }

    const float si = s_scores[i];

    // Each lane: 8 float4 groups, j4 = q*64 + lane (coalesced), 32 elems total.
    float4 e4[8];
    float partial = 0.f;
    #pragma unroll
    for (int q = 0; q < 8; ++q) {
        const int idx4 = q * 64 + lane;
        float4 sj = s4[idx4];
        const int j0 = idx4 * 4;
        float vals[4] = {sj.x, sj.y, sj.z, sj.w};
        float* ev = (float*)&e4[q];
        #pragma unroll
        for (int qq = 0; qq < 4; ++qq) {
            float d  = si - vals[qq];
            float t  = fmaf(fabsf(d), -10.0f, 5.0f);   // (0.5-|d|)/0.1
            float p  = fast_sigmoid(t);                // rel in (0,1)
            float ee = __expf(p);                      // rel<1 -> no max-sub needed
            ee = (j0 + qq < L) ? ee : 0.0f;            // masked cols -> exact 0
            ev[qq] = ee;
            partial += ee;
        }
    }

    // wave-private butterfly reduction — no LDS, no barrier
    #pragma unroll
    for (int off = 32; off > 0; off >>= 1)
        partial += __shfl_xor(partial, off, 64);
    const float inv = __builtin_amdgcn_rcpf(partial);

    #pragma unroll
    for (int q = 0; q < 8; ++q) {
        float4 o;
        o.x = e4[q].x * inv;
        o.y = e4[q].y * inv;
        o.z = e4[q].z * inv;
        o.w = e4[q].w * inv;
        orow4[q * 64 + lane] = o;
    }
}

extern "C" void kernel_launch(void* const* d_in, const int* in_sizes, int n_in,
                              void* d_out, int out_size, void* d_ws, size_t ws_size,
                              hipStream_t stream) {
    const float* logits  = (const float*)d_in[0];   // [B, T, 1] fp32
    const int*   seq_len = (const int*)d_in[1];     // [B] int32
    float*       out     = (float*)d_out;           // [B, T, T] fp32

    const int B = in_sizes[1];                      // 16
    dim3 grid(TT / WAVES, B);                       // (512, 16) = 8192 blocks
    score_branch_kernel<<<grid, dim3(BLOCK), 0, stream>>>(logits, seq_len, out);
}